// Round 11
// baseline (189.369 us; speedup 1.0000x reference)
//
#include <hip/hip_runtime.h>
#include <hip/hip_bf16.h>

#define IPB 4  // images per block (one wave = one image)

// Dequant factors: f32 weak-casts of the Python f64 scale chain.
constexpr double dDQ1 = 0.05 * 0.05;
constexpr double dDQ2 = 0.05 * 0.05 * 16.0 * 0.05;
constexpr double dDQ3 = 0.05 * 0.05 * 16.0 * 0.05 * 16.0 * 0.05;
constexpr double dDQ4 = 0.05 * 0.05 * 16.0 * 0.05 * 16.0 * 0.05 * 16.0 * 0.05;

// XLA algebraic-simplifier reciprocals: f32(1 / f32(scale_k)).
// f32(1/f32(0.05))  = 20.0 exactly
// f32(1/f32(0.04))  = 25.0 exactly
// f32(1/f32(0.032)) = 31.25 - 2^-19  (NOT 31.25!)
// f32(1/f32(0.0256))= 39.0625 exactly
#define R1f 20.0f
#define R2f 25.0f
#define R3f 31.2499980926513671875f
#define R4f 39.0625f

__device__ __forceinline__ float bf16_lo(unsigned int u) {
    u <<= 16;
    return __builtin_bit_cast(float, u);
}
__device__ __forceinline__ float bf16_hi(unsigned int u) {
    u &= 0xffff0000u;
    return __builtin_bit_cast(float, u);
}
// Round f32 -> nearest bf16 (RNE), return as f32.
__device__ __forceinline__ float bfr(float f) {
    unsigned int u = __builtin_bit_cast(unsigned int, f);
    u += 0x7fffu + ((u >> 16) & 1u);
    u &= 0xffff0000u;
    return __builtin_bit_cast(float, u);
}

__global__ __launch_bounds__(256) void qcnn_kernel(
    const void* __restrict__ xp,
    const void* __restrict__ w1p,
    const void* __restrict__ w2p,
    const void* __restrict__ w3p,
    const void* __restrict__ w4p,
    void* __restrict__ outp,
    int B)
{
    __shared__ __align__(16) float wsm[480];        // w1[0:144] w2[144:288] w3[288:432] w4[432:480]
    __shared__ __align__(16) float q1[IPB][784];    // quantized 28x28 (ch0 only; ch1-3 are zero)
    __shared__ __align__(16) float q2[IPB][676];    // 13x13x4, layout (h*13+w)*4+c
    __shared__ __align__(16) float q3[IPB][100];    // 5x5x4
    __shared__ __align__(16) float c3s[IPB][36];    // conv3 raw acc, 9 pos x 4 ch
    __shared__ __align__(16) float q4[IPB][4];

    const int tid  = threadIdx.x;
    const int slot = tid >> 6;
    const int lane = tid & 63;
    const int img  = blockIdx.x * IPB + slot;
    const bool valid = img < B;

    // ---- buffer-dtype self-detection (decode/store width only).
    bool isf32 = true;
    {
        const float* w1f = (const float*)w1p;
        #pragma unroll
        for (int i = 0; i < 16; ++i) {
            float v = w1f[i];
            isf32 = isf32 && (rintf(v) == v) && (fabsf(v) <= 8.f);
        }
    }

    const float DQ1 = (float)dDQ1;
    const float DQ2 = (float)dDQ2;
    const float DQ3 = (float)dDQ3;
    const float DQ4 = (float)dDQ4;

    // ---- load weights to LDS as f32 (small integers: exact either way) ----
    for (int i = tid; i < 480; i += 256) {
        int off = i;
        const void* wp;
        if (i < 144)      { wp = w1p; }
        else if (i < 288) { wp = w2p; off = i - 144; }
        else if (i < 432) { wp = w3p; off = i - 288; }
        else              { wp = w4p; off = i - 432; }
        float v;
        if (isf32) v = ((const float*)wp)[off];
        else       v = bf16_lo(((const unsigned short*)wp)[off]);
        wsm[i] = v;
    }

    // quant via XLA-style reciprocal multiply: clip(rne(v * r), -128, 127)
    auto quant = [&](float v, float r) -> float {
        float t = rintf(v * r);
        return fminf(fmaxf(t, -128.f), 127.f);
    };
    // pooled raw f32 int acc -> dequant (f32 mul) -> relu -> quant (recip mul).
    auto requant = [&](float m, float dq, float r) -> float {
        float y = fmaxf(m * dq, 0.f);
        return quant(y, r);
    };

    // ---- S0: load + quantize input: round(x * 20.0f) ----
    if (valid) {
        if (isf32) {
            const float4* x4 = (const float4*)((const float*)xp + (size_t)img * 784);
            for (int i = lane; i < 196; i += 64) {
                float4 v = x4[i];
                float* dst = &q1[slot][i * 4];
                dst[0] = quant(v.x, R1f);
                dst[1] = quant(v.y, R1f);
                dst[2] = quant(v.z, R1f);
                dst[3] = quant(v.w, R1f);
            }
        } else {
            const uint4* xv = (const uint4*)((const unsigned short*)xp + (size_t)img * 784);
            for (int i = lane; i < 98; i += 64) {
                uint4 v = xv[i];
                float* dst = &q1[slot][i * 8];
                const unsigned int wv[4] = {v.x, v.y, v.z, v.w};
                #pragma unroll
                for (int j = 0; j < 4; ++j) {
                    dst[2 * j]     = quant(bf16_lo(wv[j]), R1f);
                    dst[2 * j + 1] = quant(bf16_hi(wv[j]), R1f);
                }
            }
        }
    }
    __syncthreads();

    // ---- S1: conv1(3x3, ch0 only) -> maxpool2x2 -> relu -> requant : q2[676] ----
    if (valid) {
        const int oc = lane & 3;                    // invariant across c (stride 64)
        float w1r[9];
        #pragma unroll
        for (int k = 0; k < 9; ++k) w1r[k] = wsm[k * 16 + oc];  // ((k)*4+0)*4+oc
        for (int c = lane; c < 676; c += 64) {
            const int cell = c >> 2;                // 0..168
            const int ph = cell / 13, pw = cell - ph * 13;
            const int r0 = 2 * ph, c0 = 2 * pw;
            float p[4][4];
            #pragma unroll
            for (int r = 0; r < 4; ++r) {
                const float2* rp = (const float2*)&q1[slot][(r0 + r) * 28 + c0]; // 8B aligned
                float2 a = rp[0], b = rp[1];
                p[r][0] = a.x; p[r][1] = a.y; p[r][2] = b.x; p[r][3] = b.y;
            }
            float m = -__builtin_inff();
            #pragma unroll
            for (int dh = 0; dh < 2; ++dh) {
                #pragma unroll
                for (int dw = 0; dw < 2; ++dw) {
                    float a = 0.f;
                    #pragma unroll
                    for (int kh = 0; kh < 3; ++kh)
                        #pragma unroll
                        for (int kw = 0; kw < 3; ++kw)
                            a = fmaf(p[dh + kh][dw + kw], w1r[kh * 3 + kw], a);
                    m = fmaxf(m, a);                // pool raw integer accs (exact f32)
                }
            }
            q2[slot][c] = requant(m, DQ1, R2f);
        }
    }
    __syncthreads();

    // ---- S2: conv2(3x3x4) -> maxpool2x2 -> relu -> requant : q3[100] ----
    if (valid) {
        const int oc = lane & 3;
        float w2r[36];
        #pragma unroll
        for (int k = 0; k < 36; ++k) w2r[k] = wsm[144 + k * 4 + oc];
        for (int c = lane; c < 100; c += 64) {
            const int cell = c >> 2;                // 0..24
            const int ph = cell / 5, pw = cell - ph * 5;
            float p[4][4][4];                       // rows x cols x ch
            #pragma unroll
            for (int r = 0; r < 4; ++r) {
                #pragma unroll
                for (int s = 0; s < 4; ++s) {
                    const float4 v = *(const float4*)&q2[slot][((2*ph + r) * 13 + (2*pw + s)) * 4];
                    p[r][s][0] = v.x; p[r][s][1] = v.y; p[r][s][2] = v.z; p[r][s][3] = v.w;
                }
            }
            float m = -__builtin_inff();
            #pragma unroll
            for (int dh = 0; dh < 2; ++dh) {
                #pragma unroll
                for (int dw = 0; dw < 2; ++dw) {
                    float a = 0.f;
                    #pragma unroll
                    for (int kh = 0; kh < 3; ++kh)
                        #pragma unroll
                        for (int kw = 0; kw < 3; ++kw)
                            #pragma unroll
                            for (int i = 0; i < 4; ++i)
                                a = fmaf(p[dh + kh][dw + kw][i], w2r[(kh * 3 + kw) * 4 + i], a);
                    m = fmaxf(m, a);
                }
            }
            q3[slot][c] = requant(m, DQ2, R3f);
        }
    }
    __syncthreads();

    // ---- S3: conv3(3x3x4) raw accs (9 positions x 4 ch) ----
    if (valid && lane < 36) {
        const int oc = lane & 3;
        const int pos = lane >> 2;                  // 0..8
        const int oh = pos / 3, ow = pos - oh * 3;
        float a = 0.f;
        #pragma unroll
        for (int kh = 0; kh < 3; ++kh)
            #pragma unroll
            for (int kw = 0; kw < 3; ++kw)
                #pragma unroll
                for (int i = 0; i < 4; ++i)
                    a = fmaf(q3[slot][((oh + kh) * 5 + (ow + kw)) * 4 + i],
                             wsm[288 + ((kh * 3 + kw) * 4 + i) * 4 + oc], a);
        c3s[slot][lane] = a;                        // lane == pos*4+oc
    }
    __syncthreads();

    // ---- S3b: maxpool3x3 -> relu -> requant : q4[4] ----
    if (valid && lane < 4) {
        float m = -__builtin_inff();
        #pragma unroll
        for (int p = 0; p < 9; ++p) m = fmaxf(m, c3s[slot][p * 4 + lane]);
        q4[slot][lane] = requant(m, DQ3, R4f);
    }
    __syncthreads();

    // ---- S4: conv4 (1x1, 4->12, keep first 10) -> dequant -> relu -> bf16-grid store ----
    if (valid && lane < 10) {
        float a = 0.f;
        #pragma unroll
        for (int i = 0; i < 4; ++i)
            a = fmaf(q4[slot][i], wsm[432 + i * 12 + lane], a);
        float y = fmaxf(a * DQ4, 0.f);
        y = bfr(y);                                 // expected stored as bf16 in dataset
        if (isf32) ((float*)outp)[(size_t)img * 10 + lane] = y;
        else {
            unsigned int u = __builtin_bit_cast(unsigned int, y);
            ((unsigned short*)outp)[(size_t)img * 10 + lane] = (unsigned short)(u >> 16);
        }
    }
}

extern "C" void kernel_launch(void* const* d_in, const int* in_sizes, int n_in,
                              void* d_out, int out_size, void* d_ws, size_t ws_size,
                              hipStream_t stream) {
    (void)n_in; (void)d_ws; (void)ws_size; (void)out_size;
    const int B = in_sizes[0] / 784;
    const int grid = (B + IPB - 1) / IPB;
    qcnn_kernel<<<grid, 256, 0, stream>>>(d_in[0], d_in[1], d_in[2], d_in[3], d_in[4],
                                          d_out, B);
}

// Round 12
// 169.188 us; speedup vs baseline: 1.1193x; 1.1193x over previous
//
#include <hip/hip_runtime.h>
#include <hip/hip_bf16.h>

#define IPB 4  // images per block (one wave = one image)

// Dequant factors: f32 weak-casts of the Python f64 scale chain (proven R11).
constexpr double dDQ1 = 0.05 * 0.05;
constexpr double dDQ2 = 0.05 * 0.05 * 16.0 * 0.05;
constexpr double dDQ3 = 0.05 * 0.05 * 16.0 * 0.05 * 16.0 * 0.05;
constexpr double dDQ4 = 0.05 * 0.05 * 16.0 * 0.05 * 16.0 * 0.05 * 16.0 * 0.05;

// XLA algebraic-simplifier reciprocals: f32(1 / f32(scale_k)) (proven R11).
#define R1f 20.0f
#define R2f 25.0f
#define R3f 31.2499980926513671875f
#define R4f 39.0625f

#if __has_builtin(__builtin_amdgcn_sdot4)
__device__ __forceinline__ int dot4(int a, int b, int c) {
    return __builtin_amdgcn_sdot4(a, b, c, false);
}
#else
__device__ __forceinline__ int dot4(int a, int b, int c) {
    #pragma unroll
    for (int k = 0; k < 4; ++k)
        c += (int)(signed char)(a >> (8 * k)) * (int)(signed char)(b >> (8 * k));
    return c;
}
#endif

// Round f32 -> nearest bf16 (RNE), return as f32 (golden's final cast).
__device__ __forceinline__ float bfr(float f) {
    unsigned int u = __builtin_bit_cast(unsigned int, f);
    u += 0x7fffu + ((u >> 16) & 1u);
    u &= 0xffff0000u;
    return __builtin_bit_cast(float, u);
}

// ---- prep kernel: pack integer weights as char4 dwords into d_ws ----
// layout: [0..23] w1pk[oc*6 + r*2 + sh]  (3x3 conv, ch0 only; sh = window byte shift)
//         [24..59] w2pk[tap*4 + oc]      (taps = kh*3+kw, 4 input ch packed)
//         [60..95] w3pk[tap*4 + oc]
//         [96..107] w4pk[col]            (4 input ch packed, col = 0..11)
__global__ void qcnn_prep(const float* __restrict__ w1, const float* __restrict__ w2,
                          const float* __restrict__ w3, const float* __restrict__ w4,
                          int* __restrict__ wpk) {
    int t = threadIdx.x;
    if (t < 24) {
        int oc = t / 6, rem = t % 6, r = rem >> 1, sh = rem & 1;
        int v = 0;
        #pragma unroll
        for (int k = 0; k < 4; ++k) {
            int kw = k - sh;
            int w = (kw >= 0 && kw < 3) ? (int)w1[(r * 3 + kw) * 16 + oc] : 0;
            v |= (w & 0xff) << (8 * k);
        }
        wpk[t] = v;
    } else if (t < 60) {
        int e = t - 24, tap = e >> 2, oc = e & 3, v = 0;
        #pragma unroll
        for (int k = 0; k < 4; ++k) v |= (((int)w2[tap * 16 + k * 4 + oc]) & 0xff) << (8 * k);
        wpk[t] = v;
    } else if (t < 96) {
        int e = t - 60, tap = e >> 2, oc = e & 3, v = 0;
        #pragma unroll
        for (int k = 0; k < 4; ++k) v |= (((int)w3[tap * 16 + k * 4 + oc]) & 0xff) << (8 * k);
        wpk[t] = v;
    } else if (t < 108) {
        int col = t - 96, v = 0;
        #pragma unroll
        for (int k = 0; k < 4; ++k) v |= (((int)w4[k * 12 + col]) & 0xff) << (8 * k);
        wpk[t] = v;
    }
}

__global__ __launch_bounds__(256) void qcnn_main(
    const float* __restrict__ x,
    const int* __restrict__ wpk,
    float* __restrict__ out, int B)
{
    // packed int8 activations (values always in [0,127] post-quant)
    __shared__ int q1a[IPB][196];   // 28 rows x 7 dwords (cols 4j..4j+3)
    __shared__ int q1b[IPB][196];   // shifted copy: dword j = cols 4j+2..4j+5 (j=0..5 used)
    __shared__ int q2c[IPB][169];   // 13x13 cells, char4 over oc
    __shared__ int q3c[IPB][25];    // 5x5 cells, char4 over oc
    __shared__ int c3s[IPB][36];    // conv3 raw int accs, pos*4+oc
    __shared__ int q4d[IPB];        // char4 over oc

    const int tid = threadIdx.x, slot = tid >> 6, lane = tid & 63;
    const int img = blockIdx.x * IPB + slot;
    const bool valid = img < B;
    const float DQ1 = (float)dDQ1, DQ2 = (float)dDQ2, DQ3 = (float)dDQ3, DQ4 = (float)dDQ4;

    // ---- S0: quantize input (round(x*20), x in [0,1) so t in [0,20]) + pack ----
    if (valid) {
        const float4* x4 = (const float4*)(x + (size_t)img * 784);
        for (int g = lane; g < 196; g += 64) {
            float4 v = x4[g];
            int b0 = (int)fminf(rintf(v.x * R1f), 127.f);
            int b1 = (int)fminf(rintf(v.y * R1f), 127.f);
            int b2 = (int)fminf(rintf(v.z * R1f), 127.f);
            int b3 = (int)fminf(rintf(v.w * R1f), 127.f);
            q1a[slot][g] = b0 | (b1 << 8) | (b2 << 16) | (b3 << 24);
        }
    }
    __syncthreads();
    // shifted-by-2 copy for odd-aligned conv1 windows
    if (valid) {
        for (int n = lane; n < 168; n += 64) {
            int row = n / 6, j = n - row * 6;
            unsigned a = (unsigned)q1a[slot][row * 7 + j];
            unsigned b = (unsigned)q1a[slot][row * 7 + j + 1];
            q1b[slot][row * 7 + j] = (int)((a >> 16) | (b << 16));
        }
    }
    __syncthreads();

    // ---- S1: conv1 -> pool2x2 -> relu -> requant : q2c[169] (per 13x13 cell) ----
    if (valid) {
        int W1[24];
        #pragma unroll
        for (int i = 0; i < 24; ++i) W1[i] = wpk[i];
        for (int cell = lane; cell < 169; cell += 64) {
            int ph = cell / 13, pw = cell - ph * 13;
            int r0 = 2 * ph, c0 = 2 * pw;
            // patch dword covering cols c0..c0+3 for rows r0..r0+3
            const char* bp = (const char*)((c0 & 2) ? q1b[slot] : q1a[slot])
                             + r0 * 28 + (c0 & ~3);
            int rw0 = *(const int*)(bp);
            int rw1 = *(const int*)(bp + 28);
            int rw2 = *(const int*)(bp + 56);
            int rw3 = *(const int*)(bp + 84);
            int outb = 0;
            #pragma unroll
            for (int oc = 0; oc < 4; ++oc) {
                int a00 = 0, a01 = 0, a10 = 0, a11 = 0;
                #pragma unroll
                for (int r = 0; r < 3; ++r) {
                    int rwA = (r == 0) ? rw0 : ((r == 1) ? rw1 : rw2);
                    int rwB = (r == 0) ? rw1 : ((r == 1) ? rw2 : rw3);
                    a00 = dot4(rwA, W1[oc * 6 + r * 2 + 0], a00);
                    a01 = dot4(rwA, W1[oc * 6 + r * 2 + 1], a01);
                    a10 = dot4(rwB, W1[oc * 6 + r * 2 + 0], a10);
                    a11 = dot4(rwB, W1[oc * 6 + r * 2 + 1], a11);
                }
                int m = max(max(a00, a01), max(a10, a11));   // pool raw int accs
                float y = fmaxf((float)m * DQ1, 0.f);        // dequant+relu (y>=0)
                float t = fminf(rintf(y * R2f), 127.f);      // quant (t>=0)
                outb |= ((int)t) << (8 * oc);
            }
            q2c[slot][cell] = outb;
        }
    }
    __syncthreads();

    // ---- S2: conv2 -> pool2x2 -> relu -> requant : q3c[25]; item=(cell,pos) ----
    {
        int W2[36];
        #pragma unroll
        for (int i = 0; i < 36; ++i) W2[i] = wpk[24 + i];
        #pragma unroll
        for (int base_it = 0; base_it < 128; base_it += 64) {
            int it = base_it + lane;
            int a0 = 0, a1 = 0, a2 = 0, a3 = 0;
            int cell = 0, pos = 0;
            bool act = valid && it < 100;
            if (act) {
                cell = it >> 2; pos = it & 3;
                int ph = cell / 5, pw = cell - ph * 5;
                int ib = (2 * ph + (pos >> 1)) * 13 + 2 * pw + (pos & 1);
                const int* p = &q2c[slot][ib];
                #pragma unroll
                for (int kh = 0; kh < 3; ++kh)
                    #pragma unroll
                    for (int kw = 0; kw < 3; ++kw) {
                        int d = p[kh * 13 + kw];
                        a0 = dot4(d, W2[(kh * 3 + kw) * 4 + 0], a0);
                        a1 = dot4(d, W2[(kh * 3 + kw) * 4 + 1], a1);
                        a2 = dot4(d, W2[(kh * 3 + kw) * 4 + 2], a2);
                        a3 = dot4(d, W2[(kh * 3 + kw) * 4 + 3], a3);
                    }
            }
            // pool across the pos-quad (quads are fully active or fully inactive)
            int m0 = a0, m1 = a1, m2 = a2, m3 = a3;
            m0 = max(m0, __shfl_xor(m0, 1)); m0 = max(m0, __shfl_xor(m0, 2));
            m1 = max(m1, __shfl_xor(m1, 1)); m1 = max(m1, __shfl_xor(m1, 2));
            m2 = max(m2, __shfl_xor(m2, 1)); m2 = max(m2, __shfl_xor(m2, 2));
            m3 = max(m3, __shfl_xor(m3, 1)); m3 = max(m3, __shfl_xor(m3, 2));
            if (act && pos == 0) {
                int outb = 0;
                int mm[4] = {m0, m1, m2, m3};
                #pragma unroll
                for (int oc = 0; oc < 4; ++oc) {
                    float y = fmaxf((float)mm[oc] * DQ2, 0.f);
                    float t = fminf(rintf(y * R3f), 127.f);
                    outb |= ((int)t) << (8 * oc);
                }
                q3c[slot][cell] = outb;
            }
        }
    }
    __syncthreads();

    // ---- S3: conv3 raw accs (9 pos x 4 oc) ----
    if (valid && lane < 36) {
        int oc = lane & 3, pos = lane >> 2;
        int oh = pos / 3, ow = pos - oh * 3;
        const int* p = &q3c[slot][oh * 5 + ow];
        int a = 0;
        #pragma unroll
        for (int kh = 0; kh < 3; ++kh)
            #pragma unroll
            for (int kw = 0; kw < 3; ++kw)
                a = dot4(p[kh * 5 + kw], wpk[60 + (kh * 3 + kw) * 4 + oc], a);
        c3s[slot][lane] = a;
    }
    __syncthreads();

    // ---- S3b: pool3x3 -> relu -> requant : q4d ----
    if (valid && lane < 4) {
        int m = c3s[slot][lane];
        #pragma unroll
        for (int p2 = 1; p2 < 9; ++p2) m = max(m, c3s[slot][p2 * 4 + lane]);
        float y = fmaxf((float)m * DQ3, 0.f);
        float t = fminf(rintf(y * R4f), 127.f);
        ((char*)&q4d[slot])[lane] = (char)(int)t;
    }
    __syncthreads();

    // ---- S4: conv4 (1x1, 4->12, keep 10) -> dequant -> relu -> bf16-grid store ----
    if (valid && lane < 10) {
        int a = dot4(q4d[slot], wpk[96 + lane], 0);
        float y = fmaxf((float)a * DQ4, 0.f);
        out[(size_t)img * 10 + lane] = bfr(y);
    }
}

extern "C" void kernel_launch(void* const* d_in, const int* in_sizes, int n_in,
                              void* d_out, int out_size, void* d_ws, size_t ws_size,
                              hipStream_t stream) {
    (void)n_in; (void)ws_size; (void)out_size;
    const float* x  = (const float*)d_in[0];
    const float* w1 = (const float*)d_in[1];
    const float* w2 = (const float*)d_in[2];
    const float* w3 = (const float*)d_in[3];
    const float* w4 = (const float*)d_in[4];
    int* wpk = (int*)d_ws;
    float* out = (float*)d_out;

    const int B = in_sizes[0] / 784;
    qcnn_prep<<<1, 128, 0, stream>>>(w1, w2, w3, w4, wpk);
    qcnn_main<<<(B + IPB - 1) / IPB, 256, 0, stream>>>(x, wpk, out, B);
}

// Round 13
// 161.317 us; speedup vs baseline: 1.1739x; 1.0488x over previous
//
#include <hip/hip_runtime.h>
#include <hip/hip_bf16.h>

#define IPB 4  // images per block; one wave per image, waves fully independent

// Dequant factors: f32 weak-casts of the Python f64 scale chain (proven R11).
constexpr double dDQ1 = 0.05 * 0.05;
constexpr double dDQ2 = 0.05 * 0.05 * 16.0 * 0.05;
constexpr double dDQ3 = 0.05 * 0.05 * 16.0 * 0.05 * 16.0 * 0.05;
constexpr double dDQ4 = 0.05 * 0.05 * 16.0 * 0.05 * 16.0 * 0.05 * 16.0 * 0.05;

// XLA algebraic-simplifier reciprocals: f32(1 / f32(scale_k)) (proven R11).
#define R1f 20.0f
#define R2f 25.0f
#define R3f 31.2499980926513671875f
#define R4f 39.0625f

#if __has_builtin(__builtin_amdgcn_sdot4)
__device__ __forceinline__ int dot4(int a, int b, int c) {
    return __builtin_amdgcn_sdot4(a, b, c, false);
}
#else
__device__ __forceinline__ int dot4(int a, int b, int c) {
    #pragma unroll
    for (int k = 0; k < 4; ++k)
        c += (int)(signed char)(a >> (8 * k)) * (int)(signed char)(b >> (8 * k));
    return c;
}
#endif

// wave-local LDS ordering: s_waitcnt lgkmcnt(0) + compiler fence, NO s_barrier.
// All LDS buffers are wave-private (slot-indexed); intra-wave DS ops are
// in-order and the waitcnt drains them — block waves stay decoupled.
__device__ __forceinline__ void wave_fence() {
    __builtin_amdgcn_fence(__ATOMIC_ACQ_REL, "workgroup");
}

// Round f32 -> nearest bf16 (RNE), return as f32 (golden's final cast).
__device__ __forceinline__ float bfr(float f) {
    unsigned int u = __builtin_bit_cast(unsigned int, f);
    u += 0x7fffu + ((u >> 16) & 1u);
    u &= 0xffff0000u;
    return __builtin_bit_cast(float, u);
}

// quantize 4 input pixels (x in [0,1) => t = rint(20x) in [0,20], no clamp needed)
__device__ __forceinline__ int packq(float4 v) {
    int b0 = (int)rintf(v.x * R1f);
    int b1 = (int)rintf(v.y * R1f);
    int b2 = (int)rintf(v.z * R1f);
    int b3 = (int)rintf(v.w * R1f);
    return b0 | (b1 << 8) | (b2 << 16) | (b3 << 24);
}

// ---- prep kernel: pack integer weights as char4 dwords into d_ws ----
__global__ void qcnn_prep(const float* __restrict__ w1, const float* __restrict__ w2,
                          const float* __restrict__ w3, const float* __restrict__ w4,
                          int* __restrict__ wpk) {
    int t = threadIdx.x;
    if (t < 24) {
        int oc = t / 6, rem = t % 6, r = rem >> 1, sh = rem & 1;
        int v = 0;
        #pragma unroll
        for (int k = 0; k < 4; ++k) {
            int kw = k - sh;
            int w = (kw >= 0 && kw < 3) ? (int)w1[(r * 3 + kw) * 16 + oc] : 0;
            v |= (w & 0xff) << (8 * k);
        }
        wpk[t] = v;
    } else if (t < 60) {
        int e = t - 24, tap = e >> 2, oc = e & 3, v = 0;
        #pragma unroll
        for (int k = 0; k < 4; ++k) v |= (((int)w2[tap * 16 + k * 4 + oc]) & 0xff) << (8 * k);
        wpk[t] = v;
    } else if (t < 96) {
        int e = t - 60, tap = e >> 2, oc = e & 3, v = 0;
        #pragma unroll
        for (int k = 0; k < 4; ++k) v |= (((int)w3[tap * 16 + k * 4 + oc]) & 0xff) << (8 * k);
        wpk[t] = v;
    } else if (t < 108) {
        int col = t - 96, v = 0;
        #pragma unroll
        for (int k = 0; k < 4; ++k) v |= (((int)w4[k * 12 + col]) & 0xff) << (8 * k);
        wpk[t] = v;
    }
}

__global__ __launch_bounds__(256, 8) void qcnn_main(
    const float* __restrict__ x,
    const int* __restrict__ wpk,
    float* __restrict__ out, int B)
{
    __shared__ int q1a[IPB][196];   // 28 rows x 7 dwords (cols 4j..4j+3)
    __shared__ int q1b[IPB][196];   // shifted: dword j = cols 4j+2..4j+5 (j=0..5)
    __shared__ int q2c[IPB][169];   // 13x13 cells, char4 over oc
    __shared__ int q3c[IPB][25];    // 5x5 cells, char4 over oc
    __shared__ int c3s[IPB][36];    // conv3 raw int accs, pos*4+oc
    __shared__ int q4d[IPB];        // char4 over oc

    const int tid = threadIdx.x, slot = tid >> 6, lane = tid & 63;
    const int img = blockIdx.x * IPB + slot;
    const bool valid = img < B;
    const float DQ1 = (float)dDQ1, DQ2 = (float)dDQ2, DQ3 = (float)dDQ3, DQ4 = (float)dDQ4;

    // ---- S0: quantize input; front-load the 3-4 global reads (vmcnt overlap) ----
    if (valid) {
        const float4* x4 = (const float4*)(x + (size_t)img * 784);
        float4 v0 = x4[lane];
        float4 v1 = x4[lane + 64];
        float4 v2 = x4[lane + 128];
        float4 v3 = (lane < 4) ? x4[lane + 192] : make_float4(0.f, 0.f, 0.f, 0.f);
        q1a[slot][lane]       = packq(v0);
        q1a[slot][lane + 64]  = packq(v1);
        q1a[slot][lane + 128] = packq(v2);
        if (lane < 4) q1a[slot][lane + 192] = packq(v3);
    }
    wave_fence();

    // shifted-by-2 copy for odd-aligned conv1 windows
    if (valid) {
        #pragma unroll
        for (int i = 0; i < 3; ++i) {
            int n = lane + 64 * i;
            if (n < 168) {
                int row = n / 6, j = n - row * 6;
                unsigned a = (unsigned)q1a[slot][row * 7 + j];
                unsigned b = (unsigned)q1a[slot][row * 7 + j + 1];
                q1b[slot][row * 7 + j] = (int)((a >> 16) | (b << 16));
            }
        }
    }
    wave_fence();

    // ---- S1: conv1 -> pool2x2 -> relu -> requant : q2c[169] ----
    if (valid) {
        int W1[24];
        #pragma unroll
        for (int i = 0; i < 24; ++i) W1[i] = wpk[i];
        #pragma unroll
        for (int it = 0; it < 3; ++it) {
            int cell = lane + 64 * it;
            if (cell < 169) {
                int ph = cell / 13, pw = cell - ph * 13;
                int r0 = 2 * ph, c0 = 2 * pw;
                const char* bp = (const char*)((c0 & 2) ? q1b[slot] : q1a[slot])
                                 + r0 * 28 + (c0 & ~3);
                int rw0 = *(const int*)(bp);
                int rw1 = *(const int*)(bp + 28);
                int rw2 = *(const int*)(bp + 56);
                int rw3 = *(const int*)(bp + 84);
                int outb = 0;
                #pragma unroll
                for (int oc = 0; oc < 4; ++oc) {
                    int a00 = 0, a01 = 0, a10 = 0, a11 = 0;
                    #pragma unroll
                    for (int r = 0; r < 3; ++r) {
                        int rwA = (r == 0) ? rw0 : ((r == 1) ? rw1 : rw2);
                        int rwB = (r == 0) ? rw1 : ((r == 1) ? rw2 : rw3);
                        a00 = dot4(rwA, W1[oc * 6 + r * 2 + 0], a00);
                        a01 = dot4(rwA, W1[oc * 6 + r * 2 + 1], a01);
                        a10 = dot4(rwB, W1[oc * 6 + r * 2 + 0], a10);
                        a11 = dot4(rwB, W1[oc * 6 + r * 2 + 1], a11);
                    }
                    int m = max(max(a00, a01), max(a10, a11));  // pool raw int accs
                    float y = fmaxf((float)m * DQ1, 0.f);       // dequant+relu
                    // t = rint(y*25) <= rint(3.6*25) = 90 < 127: clamp dead
                    outb |= ((int)rintf(y * R2f)) << (8 * oc);
                }
                q2c[slot][cell] = outb;
            }
        }
    }
    wave_fence();

    // ---- S2: conv2 -> pool2x2 (shfl over pos-quad) -> relu -> requant : q3c[25] ----
    {
        int W2[36];
        #pragma unroll
        for (int i = 0; i < 36; ++i) W2[i] = wpk[24 + i];
        #pragma unroll
        for (int base_it = 0; base_it < 128; base_it += 64) {
            int it = base_it + lane;
            int a0 = 0, a1 = 0, a2 = 0, a3 = 0;
            int cell = 0, pos = 0;
            bool act = valid && it < 100;
            if (act) {
                cell = it >> 2; pos = it & 3;
                int ph = cell / 5, pw = cell - ph * 5;
                int ib = (2 * ph + (pos >> 1)) * 13 + 2 * pw + (pos & 1);
                const int* p = &q2c[slot][ib];
                #pragma unroll
                for (int kh = 0; kh < 3; ++kh)
                    #pragma unroll
                    for (int kw = 0; kw < 3; ++kw) {
                        int d = p[kh * 13 + kw];
                        a0 = dot4(d, W2[(kh * 3 + kw) * 4 + 0], a0);
                        a1 = dot4(d, W2[(kh * 3 + kw) * 4 + 1], a1);
                        a2 = dot4(d, W2[(kh * 3 + kw) * 4 + 2], a2);
                        a3 = dot4(d, W2[(kh * 3 + kw) * 4 + 3], a3);
                    }
            }
            int m0 = a0, m1 = a1, m2 = a2, m3 = a3;
            m0 = max(m0, __shfl_xor(m0, 1)); m0 = max(m0, __shfl_xor(m0, 2));
            m1 = max(m1, __shfl_xor(m1, 1)); m1 = max(m1, __shfl_xor(m1, 2));
            m2 = max(m2, __shfl_xor(m2, 1)); m2 = max(m2, __shfl_xor(m2, 2));
            m3 = max(m3, __shfl_xor(m3, 1)); m3 = max(m3, __shfl_xor(m3, 2));
            if (act && pos == 0) {
                int outb = 0;
                int mm[4] = {m0, m1, m2, m3};
                #pragma unroll
                for (int oc = 0; oc < 4; ++oc) {
                    float y = fmaxf((float)mm[oc] * DQ2, 0.f);
                    float t = fminf(rintf(y * R3f), 127.f);     // clamp needed here
                    outb |= ((int)t) << (8 * oc);
                }
                q3c[slot][cell] = outb;
            }
        }
    }
    wave_fence();

    // ---- S3: conv3 raw accs (9 pos x 4 oc) ----
    if (valid && lane < 36) {
        int oc = lane & 3, pos = lane >> 2;
        int oh = pos / 3, ow = pos - oh * 3;
        const int* p = &q3c[slot][oh * 5 + ow];
        int a = 0;
        #pragma unroll
        for (int kh = 0; kh < 3; ++kh)
            #pragma unroll
            for (int kw = 0; kw < 3; ++kw)
                a = dot4(p[kh * 5 + kw], wpk[60 + (kh * 3 + kw) * 4 + oc], a);
        c3s[slot][lane] = a;
    }
    wave_fence();

    // ---- S3b: pool3x3 -> relu -> requant : q4d ----
    if (valid && lane < 4) {
        int m = c3s[slot][lane];
        #pragma unroll
        for (int p2 = 1; p2 < 9; ++p2) m = max(m, c3s[slot][p2 * 4 + lane]);
        float y = fmaxf((float)m * DQ3, 0.f);
        float t = fminf(rintf(y * R4f), 127.f);                 // clamp needed
        ((char*)&q4d[slot])[lane] = (char)(int)t;
    }
    wave_fence();

    // ---- S4: conv4 (1x1, 4->12, keep 10) -> dequant -> relu -> bf16-grid store ----
    if (valid && lane < 10) {
        int a = dot4(q4d[slot], wpk[96 + lane], 0);
        float y = fmaxf((float)a * DQ4, 0.f);
        out[(size_t)img * 10 + lane] = bfr(y);
    }
}

extern "C" void kernel_launch(void* const* d_in, const int* in_sizes, int n_in,
                              void* d_out, int out_size, void* d_ws, size_t ws_size,
                              hipStream_t stream) {
    (void)n_in; (void)ws_size; (void)out_size;
    const float* x  = (const float*)d_in[0];
    const float* w1 = (const float*)d_in[1];
    const float* w2 = (const float*)d_in[2];
    const float* w3 = (const float*)d_in[3];
    const float* w4 = (const float*)d_in[4];
    int* wpk = (int*)d_ws;
    float* out = (float*)d_out;

    const int B = in_sizes[0] / 784;
    qcnn_prep<<<1, 128, 0, stream>>>(w1, w2, w3, w4, wpk);
    qcnn_main<<<(B + IPB - 1) / IPB, 256, 0, stream>>>(x, wpk, out, B);
}